// Round 2
// baseline (157.863 us; speedup 1.0000x reference)
//
#include <hip/hip_runtime.h>

// Upsample 2x (nearest) + horizontal 1x16 FIR (flattened 4x4 kernel), SAME pad.
// x: (32,512,512,1) fp32, kernel: 16 fp32, out: (32,1024,1024,1) fp32.
//
// Math (verified in prior session):
//  - conv is horizontal-only and upsampled rows 2r,2r+1 are identical
//    -> output rows 2r,2r+1 identical: compute once, store twice.
//  - up[p]=x[p>>1] collapses the 16-tap FIR to 9-tap (even cols) / 8-tap
//    (odd cols) polyphase filters on x; with x zero-padded by 4 each side
//    the collapsed form is exact at boundaries.
//
// This version (streaming-oriented restructure):
//  - grid-stride, 2048 blocks (G11 memory-bound grid cap); taps/halos once per block
//  - one 16B/lane load stages a full ROW-PAIR per iteration
//  - 4 nontemporal 16B stores/thread -> contiguous 16 KiB per block-iter
//  - double-buffered LDS -> single __syncthreads per pair
//  - native clang vector type (f32x4) for nontemporal builtins (HIP float4
//    is a class type and is rejected by __builtin_nontemporal_*)

#define W_IN   512
#define H_IN   512
#define NB     32
#define W_OUT  1024
#define NPAIR  (NB * H_IN / 2)   // 8192 input row-pairs
#define NBLK   2048
#define ITERS  (NPAIR / NBLK)    // 4 pairs per block

typedef float f32x4 __attribute__((ext_vector_type(4)));

__global__ __launch_bounds__(256) void upsample_blur_kernel(
    const float* __restrict__ x,
    const float* __restrict__ kern,
    float* __restrict__ out)
{
    // rows[dbuf][rowInPair][520]; data at [4..515], zero halo [0..3],[516..519]
    __shared__ float rows[2][2][520];

    const int t = threadIdx.x;   // 0..255

    // zero all four halo sets once (2 dbuf x 2 rows x 8 halo floats = 32)
    if (t < 32) {
        const int b  = t >> 4;          // dbuf
        const int rr = (t >> 3) & 1;    // row in pair
        const int i  = t & 7;
        rows[b][rr][(i < 4) ? i : (512 + i)] = 0.0f;
    }

    // flat 4x4 kernel (uniform -> scalar loads), collapsed polyphase taps
    float kf[16];
#pragma unroll
    for (int i = 0; i < 16; ++i) kf[i] = kern[i];

    float we[9], wo[8];
    we[0] = kf[0];
#pragma unroll
    for (int i = 0; i < 7; ++i) we[i + 1] = kf[2 * i + 1] + kf[2 * i + 2];
    we[8] = kf[15];
#pragma unroll
    for (int i = 0; i < 8; ++i) wo[i] = kf[2 * i] + kf[2 * i + 1];

    // staging map: thread t's 16B covers pair-local floats 4t..4t+3
    const int rsel = t >> 7;            // 0: first row of pair, 1: second
    const int csel = (4 * t) & 511;     // column within that row (multiple of 4)

    int buf = 0;
#pragma unroll
    for (int it = 0; it < ITERS; ++it) {
        const int pairIdx = blockIdx.x + it * NBLK;   // 0..NPAIR-1

        // ---- stage row-pair (2 KiB x 2) via one 16B/lane load ----
        const f32x4 xi = __builtin_nontemporal_load(
            reinterpret_cast<const f32x4*>(x + (size_t)pairIdx * (2 * W_IN)) + t);
        *reinterpret_cast<f32x4*>(&rows[buf][rsel][4 + csel]) = xi;

        __syncthreads();

        // ---- compute: thread t -> output cols 4t..4t+3 of both rows ----
        float v0[10], v1[10];
#pragma unroll
        for (int i = 0; i < 10; ++i) v0[i] = rows[buf][0][2 * t + i];
#pragma unroll
        for (int i = 0; i < 10; ++i) v1[i] = rows[buf][1][2 * t + i];

        float a0 = 0.f, a1 = 0.f, a2 = 0.f, a3 = 0.f;
        float b0 = 0.f, b1 = 0.f, b2 = 0.f, b3 = 0.f;
#pragma unroll
        for (int j = 0; j < 9; ++j) { a0 += we[j] * v0[j];     b0 += we[j] * v1[j];     }
#pragma unroll
        for (int j = 0; j < 8; ++j) { a1 += wo[j] * v0[j + 1]; b1 += wo[j] * v1[j + 1]; }
#pragma unroll
        for (int j = 0; j < 9; ++j) { a2 += we[j] * v0[j + 1]; b2 += we[j] * v1[j + 1]; }
#pragma unroll
        for (int j = 0; j < 8; ++j) { a3 += wo[j] * v0[j + 2]; b3 += wo[j] * v1[j + 2]; }

        f32x4 oa; oa.x = a0; oa.y = a1; oa.z = a2; oa.w = a3;
        f32x4 ob; ob.x = b0; ob.y = b1; ob.z = b2; ob.w = b3;

        // input row 2*pairIdx -> output rows 4*pairIdx .. 4*pairIdx+3 (contiguous)
        f32x4* o4 = reinterpret_cast<f32x4*>(out + (size_t)pairIdx * (4 * W_OUT));
        __builtin_nontemporal_store(oa, o4 + t);          // row 4p
        __builtin_nontemporal_store(oa, o4 + 256 + t);    // row 4p+1 (dup)
        __builtin_nontemporal_store(ob, o4 + 512 + t);    // row 4p+2
        __builtin_nontemporal_store(ob, o4 + 768 + t);    // row 4p+3 (dup)

        buf ^= 1;
        // no trailing barrier: next iter writes the OTHER LDS buffer; the
        // next iteration's barrier orders reuse of this one.
    }
}

extern "C" void kernel_launch(void* const* d_in, const int* in_sizes, int n_in,
                              void* d_out, int out_size, void* d_ws, size_t ws_size,
                              hipStream_t stream) {
    const float* x    = (const float*)d_in[0];
    const float* kern = (const float*)d_in[1];
    float* out        = (float*)d_out;

    upsample_blur_kernel<<<NBLK, 256, 0, stream>>>(x, kern, out);
}